// Round 6
// baseline (266.532 us; speedup 1.0000x reference)
//
#include <hip/hip_runtime.h>

#define HW 16384   // 128*128
#define NC 256     // C
#define NB 16      // B

typedef float floatx4 __attribute__((ext_vector_type(4)));

__device__ __forceinline__ float sum4(floatx4 v) { return (v.x + v.y) + (v.z + v.w); }
__device__ __forceinline__ floatx4 ntload(const floatx4* p) {
    return __builtin_nontemporal_load(p);
}
__device__ __forceinline__ void ntstore(floatx4* p, floatx4 v) {
    __builtin_nontemporal_store(v, p);
}

// ---------------------------------------------------------------------------
// Kernel 1: global average pool. 4096 blocks x 256 threads. (frozen from R5:
// ~45-50us.) Block bc reads plane bc of BOTH tensors with nt float4 loads
// (evict-first: single-use here, keeps L3 for apply/next-replay), 16 loads
// in flight, independent partial accumulators, wave reduce, LDS combine.
// ---------------------------------------------------------------------------
__global__ __launch_bounds__(256, 4) void pool_kernel(const float* __restrict__ fft,
                                                      const float* __restrict__ multi,
                                                      float* __restrict__ pooled) {
    int bc = blockIdx.x;             // 0..4095 = b*256 + c
    int tid = threadIdx.x;
    int lane = tid & 63, wid = tid >> 6;
    const floatx4* fbase = (const floatx4*)fft + ((size_t)bc << 12) + tid;
    const floatx4* mbase = (const floatx4*)multi + ((size_t)bc << 12) + tid;

    float fs0 = 0.f, fs1 = 0.f, fs2 = 0.f, fs3 = 0.f;
    float fs4 = 0.f, fs5 = 0.f, fs6 = 0.f, fs7 = 0.f;
    float ms0 = 0.f, ms1 = 0.f, ms2 = 0.f, ms3 = 0.f;
    float ms4 = 0.f, ms5 = 0.f, ms6 = 0.f, ms7 = 0.f;

#pragma unroll
    for (int chunk = 0; chunk < 2; ++chunk) {
        const floatx4* pf = fbase + chunk * 2048;
        const floatx4* pm = mbase + chunk * 2048;
        floatx4 f0 = ntload(pf + 0),    f1 = ntload(pf + 256);
        floatx4 f2 = ntload(pf + 512),  f3 = ntload(pf + 768);
        floatx4 f4 = ntload(pf + 1024), f5 = ntload(pf + 1280);
        floatx4 f6 = ntload(pf + 1536), f7 = ntload(pf + 1792);
        floatx4 m0 = ntload(pm + 0),    m1 = ntload(pm + 256);
        floatx4 m2 = ntload(pm + 512),  m3 = ntload(pm + 768);
        floatx4 m4 = ntload(pm + 1024), m5 = ntload(pm + 1280);
        floatx4 m6 = ntload(pm + 1536), m7 = ntload(pm + 1792);
        fs0 += sum4(f0); fs1 += sum4(f1); fs2 += sum4(f2); fs3 += sum4(f3);
        fs4 += sum4(f4); fs5 += sum4(f5); fs6 += sum4(f6); fs7 += sum4(f7);
        ms0 += sum4(m0); ms1 += sum4(m1); ms2 += sum4(m2); ms3 += sum4(m3);
        ms4 += sum4(m4); ms5 += sum4(m5); ms6 += sum4(m6); ms7 += sum4(m7);
    }
    float fsum = ((fs0 + fs1) + (fs2 + fs3)) + ((fs4 + fs5) + (fs6 + fs7));
    float msum = ((ms0 + ms1) + (ms2 + ms3)) + ((ms4 + ms5) + (ms6 + ms7));

#pragma unroll
    for (int off = 32; off > 0; off >>= 1) {
        fsum += __shfl_xor(fsum, off, 64);
        msum += __shfl_xor(msum, off, 64);
    }

    __shared__ float ws[4][2];
    if (lane == 0) { ws[wid][0] = fsum; ws[wid][1] = msum; }
    __syncthreads();
    if (tid < 2) {
        float s = (ws[0][tid] + ws[1][tid]) + (ws[2][tid] + ws[3][tid]);
        int b = bc >> 8, c = bc & 255;
        pooled[b * 512 + tid * 256 + c] = s * (1.0f / HW);
    }
}

// ---------------------------------------------------------------------------
// Kernel 2a: h[b][r] = relu(sum_c pooled[b][c] * w1[r][c]),  w1: [64][512]
// ---------------------------------------------------------------------------
__global__ __launch_bounds__(256) void mlp1_kernel(const float* __restrict__ pooled,
                                                   const float* __restrict__ w1,
                                                   float* __restrict__ h) {
    int wid = (blockIdx.x << 2) | (threadIdx.x >> 6);   // 0..1023
    int lane = threadIdx.x & 63;
    int b = wid >> 6, r = wid & 63;
    const float4* w = (const float4*)(w1 + (size_t)r * 512) + (lane << 1);
    const float4* p = (const float4*)(pooled + b * 512) + (lane << 1);
    float4 wa = w[0], wb = w[1];
    float4 pa = p[0], pb = p[1];
    float s = wa.x * pa.x + wa.y * pa.y + wa.z * pa.z + wa.w * pa.w
            + wb.x * pb.x + wb.y * pb.y + wb.z * pb.z + wb.w * pb.w;
#pragma unroll
    for (int off = 32; off > 0; off >>= 1) s += __shfl_xor(s, off, 64);
    if (lane == 0) h[wid] = fmaxf(s, 0.f);
}

// ---------------------------------------------------------------------------
// Kernel 2b: attn[b][c] = sigmoid(sum_r h[b][r] * w2[c][r]),  w2: [512][64]
// ---------------------------------------------------------------------------
__global__ __launch_bounds__(256) void mlp2_kernel(const float* __restrict__ h,
                                                   const float* __restrict__ w2,
                                                   float* __restrict__ attn) {
    int wid = (blockIdx.x << 2) | (threadIdx.x >> 6);   // 0..8191
    int lane = threadIdx.x & 63;
    int b = wid >> 9, c = wid & 511;
    float s = h[(b << 6) | lane] * w2[((size_t)c << 6) | lane];
#pragma unroll
    for (int off = 32; off > 0; off >>= 1) s += __shfl_xor(s, off, 64);
    if (lane == 0) attn[(b << 9) | c] = 1.0f / (1.0f + __expf(-s));
}

// ---------------------------------------------------------------------------
// Kernel 3: out = attn[b][c]*fft + attn[b][256+c]*multi.
// EXACTLY 4096 blocks x 256 threads: thread i0 (< 2^20) handles float4s
// i0 + k*2^20 for k=0..15. Plane of element k is (b=k, c=i0>>12):
// the attn loads are wave-uniform broadcasts, and b is the unroll index.
// 4-deep named load batches (8 global loads in flight) fixes the R5
// latency-bound profile (VGPR=12, ~2 loads in flight, 190us at 2.8 TB/s).
// Stores are non-temporal: 'out' is never re-read; keep L3 for the inputs.
// ---------------------------------------------------------------------------
__global__ __launch_bounds__(256) void apply_kernel(const float* __restrict__ fft,
                                                    const float* __restrict__ multi,
                                                    const float* __restrict__ attn,
                                                    float* __restrict__ out) {
    const floatx4* f4 = (const floatx4*)fft;
    const floatx4* m4 = (const floatx4*)multi;
    floatx4* o4 = (floatx4*)out;
    const size_t stride = (size_t)1 << 20;             // 4096*256 threads
    size_t i0 = (size_t)blockIdx.x * 256 + threadIdx.x;
    int c = (int)(i0 >> 12);                           // wave-uniform channel

#pragma unroll
    for (int outer = 0; outer < 4; ++outer) {
        size_t ia = i0 + (size_t)(4 * outer + 0) * stride;
        size_t ib = i0 + (size_t)(4 * outer + 1) * stride;
        size_t ic = i0 + (size_t)(4 * outer + 2) * stride;
        size_t id = i0 + (size_t)(4 * outer + 3) * stride;
        // 8 independent global loads issued back-to-back
        floatx4 fa = f4[ia], fb = f4[ib], fc = f4[ic], fd = f4[id];
        floatx4 ma = m4[ia], mb = m4[ib], mc = m4[ic], md = m4[id];
        // broadcast attn weights (b = 4*outer+j), L1/L2-resident 8KB table
        int ba = 4 * outer;
        float fwa = attn[(ba + 0) * 512 + c],       fwb = attn[(ba + 1) * 512 + c];
        float fwc = attn[(ba + 2) * 512 + c],       fwd = attn[(ba + 3) * 512 + c];
        float mwa = attn[(ba + 0) * 512 + 256 + c], mwb = attn[(ba + 1) * 512 + 256 + c];
        float mwc = attn[(ba + 2) * 512 + 256 + c], mwd = attn[(ba + 3) * 512 + 256 + c];
        floatx4 oa, ob, oc, od;
        oa.x = fmaf(fwa, fa.x, mwa * ma.x); oa.y = fmaf(fwa, fa.y, mwa * ma.y);
        oa.z = fmaf(fwa, fa.z, mwa * ma.z); oa.w = fmaf(fwa, fa.w, mwa * ma.w);
        ob.x = fmaf(fwb, fb.x, mwb * mb.x); ob.y = fmaf(fwb, fb.y, mwb * mb.y);
        ob.z = fmaf(fwb, fb.z, mwb * mb.z); ob.w = fmaf(fwb, fb.w, mwb * mb.w);
        oc.x = fmaf(fwc, fc.x, mwc * mc.x); oc.y = fmaf(fwc, fc.y, mwc * mc.y);
        oc.z = fmaf(fwc, fc.z, mwc * mc.z); oc.w = fmaf(fwc, fc.w, mwc * mc.w);
        od.x = fmaf(fwd, fd.x, mwd * md.x); od.y = fmaf(fwd, fd.y, mwd * md.y);
        od.z = fmaf(fwd, fd.z, mwd * md.z); od.w = fmaf(fwd, fd.w, mwd * md.w);
        ntstore(o4 + ia, oa);
        ntstore(o4 + ib, ob);
        ntstore(o4 + ic, oc);
        ntstore(o4 + id, od);
    }
}

extern "C" void kernel_launch(void* const* d_in, const int* in_sizes, int n_in,
                              void* d_out, int out_size, void* d_ws, size_t ws_size,
                              hipStream_t stream) {
    const float* fft   = (const float*)d_in[0];
    const float* multi = (const float*)d_in[1];
    const float* w1    = (const float*)d_in[2];   // [64][512]
    const float* w2    = (const float*)d_in[3];   // [512][64]
    float* out = (float*)d_out;

    float* pooled = (float*)d_ws;                 // [16][512]
    float* h      = pooled + NB * 512;            // [16][64]
    float* attn   = h + NB * 64;                  // [16][512]

    pool_kernel<<<4096, 256, 0, stream>>>(fft, multi, pooled);
    mlp1_kernel<<<256, 256, 0, stream>>>(pooled, w1, h);
    mlp2_kernel<<<2048, 256, 0, stream>>>(h, w2, attn);
    apply_kernel<<<4096, 256, 0, stream>>>(fft, multi, attn, out);
}

// Round 7
// 264.735 us; speedup vs baseline: 1.0068x; 1.0068x over previous
//
#include <hip/hip_runtime.h>

#define HW 16384   // 128*128
#define NC 256     // C
#define NB 16      // B

typedef float floatx4 __attribute__((ext_vector_type(4)));

__device__ __forceinline__ float sum4(floatx4 v) { return (v.x + v.y) + (v.z + v.w); }
__device__ __forceinline__ floatx4 ntload(const floatx4* p) {
    return __builtin_nontemporal_load(p);
}

// ---------------------------------------------------------------------------
// Kernel 1: global average pool. 4096 blocks x 256 threads. (frozen from R5:
// ~45-50us.) Block bc reads plane bc of BOTH tensors with nt float4 loads
// (evict-first: single-use here; nt loads still HIT resident L3 lines, they
// just don't allocate/evict — preserving L3 for apply), 16 loads in flight,
// independent partial accumulators, wave reduce, LDS combine.
// ---------------------------------------------------------------------------
__global__ __launch_bounds__(256, 4) void pool_kernel(const float* __restrict__ fft,
                                                      const float* __restrict__ multi,
                                                      float* __restrict__ pooled) {
    int bc = blockIdx.x;             // 0..4095 = b*256 + c
    int tid = threadIdx.x;
    int lane = tid & 63, wid = tid >> 6;
    const floatx4* fbase = (const floatx4*)fft + ((size_t)bc << 12) + tid;
    const floatx4* mbase = (const floatx4*)multi + ((size_t)bc << 12) + tid;

    float fs0 = 0.f, fs1 = 0.f, fs2 = 0.f, fs3 = 0.f;
    float fs4 = 0.f, fs5 = 0.f, fs6 = 0.f, fs7 = 0.f;
    float ms0 = 0.f, ms1 = 0.f, ms2 = 0.f, ms3 = 0.f;
    float ms4 = 0.f, ms5 = 0.f, ms6 = 0.f, ms7 = 0.f;

#pragma unroll
    for (int chunk = 0; chunk < 2; ++chunk) {
        const floatx4* pf = fbase + chunk * 2048;
        const floatx4* pm = mbase + chunk * 2048;
        floatx4 f0 = ntload(pf + 0),    f1 = ntload(pf + 256);
        floatx4 f2 = ntload(pf + 512),  f3 = ntload(pf + 768);
        floatx4 f4 = ntload(pf + 1024), f5 = ntload(pf + 1280);
        floatx4 f6 = ntload(pf + 1536), f7 = ntload(pf + 1792);
        floatx4 m0 = ntload(pm + 0),    m1 = ntload(pm + 256);
        floatx4 m2 = ntload(pm + 512),  m3 = ntload(pm + 768);
        floatx4 m4 = ntload(pm + 1024), m5 = ntload(pm + 1280);
        floatx4 m6 = ntload(pm + 1536), m7 = ntload(pm + 1792);
        fs0 += sum4(f0); fs1 += sum4(f1); fs2 += sum4(f2); fs3 += sum4(f3);
        fs4 += sum4(f4); fs5 += sum4(f5); fs6 += sum4(f6); fs7 += sum4(f7);
        ms0 += sum4(m0); ms1 += sum4(m1); ms2 += sum4(m2); ms3 += sum4(m3);
        ms4 += sum4(m4); ms5 += sum4(m5); ms6 += sum4(m6); ms7 += sum4(m7);
    }
    float fsum = ((fs0 + fs1) + (fs2 + fs3)) + ((fs4 + fs5) + (fs6 + fs7));
    float msum = ((ms0 + ms1) + (ms2 + ms3)) + ((ms4 + ms5) + (ms6 + ms7));

#pragma unroll
    for (int off = 32; off > 0; off >>= 1) {
        fsum += __shfl_xor(fsum, off, 64);
        msum += __shfl_xor(msum, off, 64);
    }

    __shared__ float ws[4][2];
    if (lane == 0) { ws[wid][0] = fsum; ws[wid][1] = msum; }
    __syncthreads();
    if (tid < 2) {
        float s = (ws[0][tid] + ws[1][tid]) + (ws[2][tid] + ws[3][tid]);
        int b = bc >> 8, c = bc & 255;
        pooled[b * 512 + tid * 256 + c] = s * (1.0f / HW);
    }
}

// ---------------------------------------------------------------------------
// Kernel 2a: h[b][r] = relu(sum_c pooled[b][c] * w1[r][c]),  w1: [64][512]
// ---------------------------------------------------------------------------
__global__ __launch_bounds__(256) void mlp1_kernel(const float* __restrict__ pooled,
                                                   const float* __restrict__ w1,
                                                   float* __restrict__ h) {
    int wid = (blockIdx.x << 2) | (threadIdx.x >> 6);   // 0..1023
    int lane = threadIdx.x & 63;
    int b = wid >> 6, r = wid & 63;
    const float4* w = (const float4*)(w1 + (size_t)r * 512) + (lane << 1);
    const float4* p = (const float4*)(pooled + b * 512) + (lane << 1);
    float4 wa = w[0], wb = w[1];
    float4 pa = p[0], pb = p[1];
    float s = wa.x * pa.x + wa.y * pa.y + wa.z * pa.z + wa.w * pa.w
            + wb.x * pb.x + wb.y * pb.y + wb.z * pb.z + wb.w * pb.w;
#pragma unroll
    for (int off = 32; off > 0; off >>= 1) s += __shfl_xor(s, off, 64);
    if (lane == 0) h[wid] = fmaxf(s, 0.f);
}

// ---------------------------------------------------------------------------
// Kernel 2b: attn[b][c] = sigmoid(sum_r h[b][r] * w2[c][r]),  w2: [512][64]
// ---------------------------------------------------------------------------
__global__ __launch_bounds__(256) void mlp2_kernel(const float* __restrict__ h,
                                                   const float* __restrict__ w2,
                                                   float* __restrict__ attn) {
    int wid = (blockIdx.x << 2) | (threadIdx.x >> 6);   // 0..8191
    int lane = threadIdx.x & 63;
    int b = wid >> 9, c = wid & 511;
    float s = h[(b << 6) | lane] * w2[((size_t)c << 6) | lane];
#pragma unroll
    for (int off = 32; off > 0; off >>= 1) s += __shfl_xor(s, off, 64);
    if (lane == 0) attn[(b << 9) | c] = 1.0f / (1.0f + __expf(-s));
}

// ---------------------------------------------------------------------------
// Kernel 3: out = attn[b][c]*fft + attn[b][256+c]*multi.
// EXACTLY 4096 blocks x 256 threads: thread i0 (< 2^20) handles float4s
// i0 + k*2^20, k=0..15. Plane of element k is (b=k, c=i0>>12): attn loads
// are wave-uniform broadcasts, b is the unroll index. 4-deep named load
// batches (8 global loads in flight) attack the R5 latency-bound profile
// (VGPR=12, ~2 loads in flight, 190us @ 2.9 TB/s). Stores are REGULAR
// caching stores — R6 proved nt-stores cost ~65us (write path loses L2
// buffering/merging; fillBuffer sustains 7 TB/s *through* the cache).
// ---------------------------------------------------------------------------
__global__ __launch_bounds__(256) void apply_kernel(const float* __restrict__ fft,
                                                    const float* __restrict__ multi,
                                                    const float* __restrict__ attn,
                                                    float* __restrict__ out) {
    const floatx4* f4 = (const floatx4*)fft;
    const floatx4* m4 = (const floatx4*)multi;
    floatx4* o4 = (floatx4*)out;
    const size_t stride = (size_t)1 << 20;             // 4096*256 threads
    size_t i0 = (size_t)blockIdx.x * 256 + threadIdx.x;
    int c = (int)(i0 >> 12);                           // wave-uniform channel

#pragma unroll
    for (int outer = 0; outer < 4; ++outer) {
        size_t ia = i0 + (size_t)(4 * outer + 0) * stride;
        size_t ib = i0 + (size_t)(4 * outer + 1) * stride;
        size_t ic = i0 + (size_t)(4 * outer + 2) * stride;
        size_t id = i0 + (size_t)(4 * outer + 3) * stride;
        // 8 independent global loads issued back-to-back
        floatx4 fa = f4[ia], fb = f4[ib], fc = f4[ic], fd = f4[id];
        floatx4 ma = m4[ia], mb = m4[ib], mc = m4[ic], md = m4[id];
        // broadcast attn weights (b = 4*outer+j), L1/L2-resident 8KB table
        int ba = 4 * outer;
        float fwa = attn[(ba + 0) * 512 + c],       fwb = attn[(ba + 1) * 512 + c];
        float fwc = attn[(ba + 2) * 512 + c],       fwd = attn[(ba + 3) * 512 + c];
        float mwa = attn[(ba + 0) * 512 + 256 + c], mwb = attn[(ba + 1) * 512 + 256 + c];
        float mwc = attn[(ba + 2) * 512 + 256 + c], mwd = attn[(ba + 3) * 512 + 256 + c];
        floatx4 oa, ob, oc, od;
        oa.x = fmaf(fwa, fa.x, mwa * ma.x); oa.y = fmaf(fwa, fa.y, mwa * ma.y);
        oa.z = fmaf(fwa, fa.z, mwa * ma.z); oa.w = fmaf(fwa, fa.w, mwa * ma.w);
        ob.x = fmaf(fwb, fb.x, mwb * mb.x); ob.y = fmaf(fwb, fb.y, mwb * mb.y);
        ob.z = fmaf(fwb, fb.z, mwb * mb.z); ob.w = fmaf(fwb, fb.w, mwb * mb.w);
        oc.x = fmaf(fwc, fc.x, mwc * mc.x); oc.y = fmaf(fwc, fc.y, mwc * mc.y);
        oc.z = fmaf(fwc, fc.z, mwc * mc.z); oc.w = fmaf(fwc, fc.w, mwc * mc.w);
        od.x = fmaf(fwd, fd.x, mwd * md.x); od.y = fmaf(fwd, fd.y, mwd * md.y);
        od.z = fmaf(fwd, fd.z, mwd * md.z); od.w = fmaf(fwd, fd.w, mwd * md.w);
        o4[ia] = oa;
        o4[ib] = ob;
        o4[ic] = oc;
        o4[id] = od;
    }
}

extern "C" void kernel_launch(void* const* d_in, const int* in_sizes, int n_in,
                              void* d_out, int out_size, void* d_ws, size_t ws_size,
                              hipStream_t stream) {
    const float* fft   = (const float*)d_in[0];
    const float* multi = (const float*)d_in[1];
    const float* w1    = (const float*)d_in[2];   // [64][512]
    const float* w2    = (const float*)d_in[3];   // [512][64]
    float* out = (float*)d_out;

    float* pooled = (float*)d_ws;                 // [16][512]
    float* h      = pooled + NB * 512;            // [16][64]
    float* attn   = h + NB * 64;                  // [16][512]

    pool_kernel<<<4096, 256, 0, stream>>>(fft, multi, pooled);
    mlp1_kernel<<<256, 256, 0, stream>>>(pooled, w1, h);
    mlp2_kernel<<<2048, 256, 0, stream>>>(h, w2, attn);
    apply_kernel<<<4096, 256, 0, stream>>>(fft, multi, attn, out);
}

// Round 8
// 216.556 us; speedup vs baseline: 1.2308x; 1.2225x over previous
//
#include <hip/hip_runtime.h>

#define HW 16384   // 128*128
#define NC 256     // C
#define NB 16      // B

typedef float floatx4 __attribute__((ext_vector_type(4)));

__device__ __forceinline__ float sum4(floatx4 v) { return (v.x + v.y) + (v.z + v.w); }
__device__ __forceinline__ floatx4 ntload(const floatx4* p) {
    return __builtin_nontemporal_load(p);
}

// ---------------------------------------------------------------------------
// CONFIG B (steady-state cache design):
//   * ALL large tensor reads are non-temporal (no L3 allocation).
//   * out stores are regular caching stores (write-allocate).
//   => In steady state L3 == the out buffer (same addresses every replay),
//      permanently dirty-resident: apply's stores are write HITS and out
//      (almost) never flows to HBM. Inputs stream from HBM at the pure-read
//      ceiling with no dirty-victim writeback entanglement (the R5/R7
//      apply-killer) and no cleanup pass (the R2 pool-killer).
// ---------------------------------------------------------------------------

// ---------------------------------------------------------------------------
// Kernel 1: global average pool. 4096 blocks x 256 threads. Block bc reads
// plane bc of BOTH tensors with nt float4 loads, 16 loads in flight,
// independent partial accumulators, wave reduce, LDS combine.
// (Binary proven to sustain ~6 TB/s effective in R5.)
// ---------------------------------------------------------------------------
__global__ __launch_bounds__(256, 4) void pool_kernel(const float* __restrict__ fft,
                                                      const float* __restrict__ multi,
                                                      float* __restrict__ pooled) {
    int bc = blockIdx.x;             // 0..4095 = b*256 + c
    int tid = threadIdx.x;
    int lane = tid & 63, wid = tid >> 6;
    const floatx4* fbase = (const floatx4*)fft + ((size_t)bc << 12) + tid;
    const floatx4* mbase = (const floatx4*)multi + ((size_t)bc << 12) + tid;

    float fs0 = 0.f, fs1 = 0.f, fs2 = 0.f, fs3 = 0.f;
    float fs4 = 0.f, fs5 = 0.f, fs6 = 0.f, fs7 = 0.f;
    float ms0 = 0.f, ms1 = 0.f, ms2 = 0.f, ms3 = 0.f;
    float ms4 = 0.f, ms5 = 0.f, ms6 = 0.f, ms7 = 0.f;

#pragma unroll
    for (int chunk = 0; chunk < 2; ++chunk) {
        const floatx4* pf = fbase + chunk * 2048;
        const floatx4* pm = mbase + chunk * 2048;
        floatx4 f0 = ntload(pf + 0),    f1 = ntload(pf + 256);
        floatx4 f2 = ntload(pf + 512),  f3 = ntload(pf + 768);
        floatx4 f4 = ntload(pf + 1024), f5 = ntload(pf + 1280);
        floatx4 f6 = ntload(pf + 1536), f7 = ntload(pf + 1792);
        floatx4 m0 = ntload(pm + 0),    m1 = ntload(pm + 256);
        floatx4 m2 = ntload(pm + 512),  m3 = ntload(pm + 768);
        floatx4 m4 = ntload(pm + 1024), m5 = ntload(pm + 1280);
        floatx4 m6 = ntload(pm + 1536), m7 = ntload(pm + 1792);
        fs0 += sum4(f0); fs1 += sum4(f1); fs2 += sum4(f2); fs3 += sum4(f3);
        fs4 += sum4(f4); fs5 += sum4(f5); fs6 += sum4(f6); fs7 += sum4(f7);
        ms0 += sum4(m0); ms1 += sum4(m1); ms2 += sum4(m2); ms3 += sum4(m3);
        ms4 += sum4(m4); ms5 += sum4(m5); ms6 += sum4(m6); ms7 += sum4(m7);
    }
    float fsum = ((fs0 + fs1) + (fs2 + fs3)) + ((fs4 + fs5) + (fs6 + fs7));
    float msum = ((ms0 + ms1) + (ms2 + ms3)) + ((ms4 + ms5) + (ms6 + ms7));

#pragma unroll
    for (int off = 32; off > 0; off >>= 1) {
        fsum += __shfl_xor(fsum, off, 64);
        msum += __shfl_xor(msum, off, 64);
    }

    __shared__ float ws[4][2];
    if (lane == 0) { ws[wid][0] = fsum; ws[wid][1] = msum; }
    __syncthreads();
    if (tid < 2) {
        float s = (ws[0][tid] + ws[1][tid]) + (ws[2][tid] + ws[3][tid]);
        int b = bc >> 8, c = bc & 255;
        pooled[b * 512 + tid * 256 + c] = s * (1.0f / HW);
    }
}

// ---------------------------------------------------------------------------
// Kernel 2a: h[b][r] = relu(sum_c pooled[b][c] * w1[r][c]),  w1: [64][512]
// ---------------------------------------------------------------------------
__global__ __launch_bounds__(256) void mlp1_kernel(const float* __restrict__ pooled,
                                                   const float* __restrict__ w1,
                                                   float* __restrict__ h) {
    int wid = (blockIdx.x << 2) | (threadIdx.x >> 6);   // 0..1023
    int lane = threadIdx.x & 63;
    int b = wid >> 6, r = wid & 63;
    const float4* w = (const float4*)(w1 + (size_t)r * 512) + (lane << 1);
    const float4* p = (const float4*)(pooled + b * 512) + (lane << 1);
    float4 wa = w[0], wb = w[1];
    float4 pa = p[0], pb = p[1];
    float s = wa.x * pa.x + wa.y * pa.y + wa.z * pa.z + wa.w * pa.w
            + wb.x * pb.x + wb.y * pb.y + wb.z * pb.z + wb.w * pb.w;
#pragma unroll
    for (int off = 32; off > 0; off >>= 1) s += __shfl_xor(s, off, 64);
    if (lane == 0) h[wid] = fmaxf(s, 0.f);
}

// ---------------------------------------------------------------------------
// Kernel 2b: attn[b][c] = sigmoid(sum_r h[b][r] * w2[c][r]),  w2: [512][64]
// ---------------------------------------------------------------------------
__global__ __launch_bounds__(256) void mlp2_kernel(const float* __restrict__ h,
                                                   const float* __restrict__ w2,
                                                   float* __restrict__ attn) {
    int wid = (blockIdx.x << 2) | (threadIdx.x >> 6);   // 0..8191
    int lane = threadIdx.x & 63;
    int b = wid >> 9, c = wid & 511;
    float s = h[(b << 6) | lane] * w2[((size_t)c << 6) | lane];
#pragma unroll
    for (int off = 32; off > 0; off >>= 1) s += __shfl_xor(s, off, 64);
    if (lane == 0) attn[(b << 9) | c] = 1.0f / (1.0f + __expf(-s));
}

// ---------------------------------------------------------------------------
// Kernel 3: out = attn[b][c]*fft + attn[b][256+c]*multi.
// EXACT R2 structure (grid-stride, 2048x256 = 32 waves/CU, VGPR~12 — the
// config that ran ~100us) with ONE change: the two tensor reads are
// non-temporal so they never allocate/evict in L3. Stores stay caching:
// in steady state they write-HIT the previous replay's dirty out lines
// (same addresses) and out stops flowing to HBM. attn reads stay caching
// (8KB broadcast table).
// ---------------------------------------------------------------------------
__global__ __launch_bounds__(256) void apply_kernel(const float* __restrict__ fft,
                                                    const float* __restrict__ multi,
                                                    const float* __restrict__ attn,
                                                    float* __restrict__ out) {
    const floatx4* f4 = (const floatx4*)fft;
    const floatx4* m4 = (const floatx4*)multi;
    floatx4* o4 = (floatx4*)out;
    const size_t total4 = (size_t)NB * NC * HW / 4;  // 16,777,216
    size_t stride = (size_t)gridDim.x * blockDim.x;
    for (size_t i = (size_t)blockIdx.x * blockDim.x + threadIdx.x; i < total4; i += stride) {
        int plane = (int)(i >> 12);          // b*256 + c
        int b = plane >> 8, c = plane & 255;
        float fw = attn[b * 512 + c];
        float mw = attn[b * 512 + 256 + c];
        floatx4 f = ntload(f4 + i);
        floatx4 m = ntload(m4 + i);
        floatx4 o;
        o.x = fmaf(fw, f.x, mw * m.x);
        o.y = fmaf(fw, f.y, mw * m.y);
        o.z = fmaf(fw, f.z, mw * m.z);
        o.w = fmaf(fw, f.w, mw * m.w);
        o4[i] = o;
    }
}

extern "C" void kernel_launch(void* const* d_in, const int* in_sizes, int n_in,
                              void* d_out, int out_size, void* d_ws, size_t ws_size,
                              hipStream_t stream) {
    const float* fft   = (const float*)d_in[0];
    const float* multi = (const float*)d_in[1];
    const float* w1    = (const float*)d_in[2];   // [64][512]
    const float* w2    = (const float*)d_in[3];   // [512][64]
    float* out = (float*)d_out;

    float* pooled = (float*)d_ws;                 // [16][512]
    float* h      = pooled + NB * 512;            // [16][64]
    float* attn   = h + NB * 64;                  // [16][512]

    pool_kernel<<<4096, 256, 0, stream>>>(fft, multi, pooled);
    mlp1_kernel<<<256, 256, 0, stream>>>(pooled, w1, h);
    mlp2_kernel<<<2048, 256, 0, stream>>>(h, w2, attn);
    apply_kernel<<<2048, 256, 0, stream>>>(fft, multi, attn, out);
}